// Round 8
// baseline (1411.542 us; speedup 1.0000x reference)
//
#include <hip/hip_runtime.h>
#include <float.h>

#define Bz   4
#define Cz   128
#define Nz   8192
#define Kz   20
#define OUTz 128

// ---------------------------------------------------------------------------
// Kernel 1: xx[b*N+n] = sum_c x[b][c][n]^2   (unchanged)
// ---------------------------------------------------------------------------
__global__ __launch_bounds__(256) void xx_kernel(const float* __restrict__ x,
                                                 float* __restrict__ xx) {
    int t = blockIdx.x * 256 + threadIdx.x;          // 0 .. B*N-1
    int b = t >> 13;
    int n = t & (Nz - 1);
    const float* xp = x + (size_t)b * Cz * Nz + n;
    float s = 0.f;
#pragma unroll 8
    for (int c = 0; c < Cz; ++c) {
        float v = xp[(size_t)c * Nz];
        s = fmaf(v, v, s);
    }
    xx[t] = s;
}

// ---------------------------------------------------------------------------
// Kernel 2: fused pairwise-score GEMM + per-row top-20, KEY-SPLIT 2-WAY.
// Grid (N/64, B, 2): blockIdx.z selects keys [z*4096, z*4096+4096).
// Round 7 showed grid=512 caps the machine at 2 blocks/CU (Occupancy 20%)
// while LDS (48KB) would allow 3 -> split keys to get 1024 blocks.
// Block tile 64q x 256k, per-thread 8x8, keys {tx*4..+3, 128+tx*4..+3}
// (conflict-free b128 phases). LDS 48KB: Ald 32KB resident + buf2 16KB
// (double-buffered B chunks; score tile 64x64 aliases it during selection).
// Partial top-20 (values AND indices) written to scratch; merge_kernel
// combines halves exactly. Per-pair fp32 chain (ascending c, single
// fmaf(query,key,acc), 2*acc-xx, ascending-j strict-> selection within the
// half) IDENTICAL to rounds 1-7 -> bit-identical partial lists.
// ---------------------------------------------------------------------------
__global__ __launch_bounds__(256) void knn_kernel(const float* __restrict__ x,
                                                  const float* __restrict__ xxg,
                                                  float* __restrict__ pval,
                                                  int* __restrict__ pidx) {
    const int b  = blockIdx.y;
    const int q0 = blockIdx.x * 64;
    const int hz = blockIdx.z;
    const int kb = hz * (Nz / 2);

    __shared__ __align__(16) float Ald[128 * 64];     // 32KB [c][q]
    __shared__ __align__(16) float buf2[2 * 8 * 256]; // 16KB
    float* bufA = buf2;            // 8KB [c][k]
    float* bufB = buf2 + 2048;     // 8KB [c][k]
    float* sc   = buf2;            // 16KB [64q][64col rot]  (aliased)

    const int tid  = threadIdx.x;
    const int tx   = tid & 31;      // key group
    const int ty   = tid >> 5;      // query octet (also staging c-row)
    const int lane = tid & 63;
    const int wid  = tid >> 6;

    const float* xb = x + (size_t)b * Cz * Nz;

    // stage A once: Ald[c][q] = x[b][c][q0+q]
    {
        int q4 = (tid & 15) * 4;
        int c0 = tid >> 4;          // 0..15
#pragma unroll
        for (int rep = 0; rep < 8; ++rep) {
            int c = c0 + rep * 16;
            *(float4*)&Ald[c * 64 + q4] =
                *(const float4*)&xb[(size_t)c * Nz + q0 + q4];
        }
    }
    // visibility covered by the first chunk's __syncthreads

    // top-20 state: owner = lane<16 of each wave, row orow
    float tv[Kz];
    int   ti[Kz];
#pragma unroll
    for (int s = 0; s < Kz; ++s) { tv[s] = -FLT_MAX; ti[s] = 0; }
    float wv = -FLT_MAX;
    int wslot = 0;
    const int orow = wid * 16 + lane;            // owner row (lane<16)
    const int srow = wid * 16 + (lane & 15);     // scanned row (all lanes)
    const int part = lane >> 4;                  // 16-col part (0..3)

    float4 st0[2], st1[2];

#define LOADCHUNK(dst, kj, ch)                                                \
    {                                                                         \
        _Pragma("unroll")                                                     \
        for (int i = 0; i < 2; ++i)                                           \
            dst[i] = *(const float4*)&xb[(size_t)((ch) * 8 + ty) * Nz + (kj) + tx * 4 + i * 128]; \
    }

#define WRITECHUNK(src, buf)                                                  \
    {                                                                         \
        _Pragma("unroll")                                                     \
        for (int i = 0; i < 2; ++i)                                           \
            *(float4*)&(buf)[ty * 256 + tx * 4 + i * 128] = src[i];           \
    }

#define COMPUTECHUNK(buf, ch)                                                 \
    {                                                                         \
        _Pragma("unroll")                                                     \
        for (int cc = 0; cc < 8; ++cc) {                                      \
            float4 a0 = *(const float4*)&Ald[((ch) * 8 + cc) * 64 + ty * 8];  \
            float4 a1 = *(const float4*)&Ald[((ch) * 8 + cc) * 64 + ty * 8 + 4]; \
            float4 b0 = *(const float4*)&(buf)[cc * 256 + tx * 4];            \
            float4 b1 = *(const float4*)&(buf)[cc * 256 + 128 + tx * 4];      \
            float av[8] = {a0.x, a0.y, a0.z, a0.w, a1.x, a1.y, a1.z, a1.w};   \
            float bv[8] = {b0.x, b0.y, b0.z, b0.w, b1.x, b1.y, b1.z, b1.w};   \
            _Pragma("unroll")                                                 \
            for (int q = 0; q < 8; ++q) {                                     \
                _Pragma("unroll")                                             \
                for (int k = 0; k < 8; ++k)                                   \
                    acc[q][k] = fmaf(av[q], bv[k], acc[q][k]);                \
            }                                                                 \
        }                                                                     \
    }

#define EXTRACT(pm_, gbase_)                                                  \
    {                                                                         \
        unsigned long long pm = (pm_);                                        \
        while (pm) {                                                          \
            int j = __ffsll(pm) - 1;                                          \
            pm &= pm - 1;                                                     \
            float s = sc[orow * 64 + ((j + 4 * orow) & 63)];                  \
            if (s > wv) {                                                     \
                int gj = (gbase_) + j;                                        \
                _Pragma("unroll")                                             \
                for (int s2 = 0; s2 < Kz; ++s2) {                             \
                    bool hit = (s2 == wslot);                                 \
                    tv[s2] = hit ? s : tv[s2];                                \
                    ti[s2] = hit ? gj : ti[s2];                               \
                }                                                             \
                wv = tv[0]; wslot = 0;                                        \
                _Pragma("unroll")                                             \
                for (int s2 = 1; s2 < Kz; ++s2)                               \
                    if (tv[s2] < wv) { wv = tv[s2]; wslot = s2; }             \
            }                                                                 \
        }                                                                     \
    }

    // prologue: tile 0, chunk 0
    LOADCHUNK(st0, kb, 0);

#pragma unroll 1
    for (int kt = 0; kt < Nz / 2 / 256; ++kt) {
        const int kj0 = kb + kt * 256;
        const int kjn = kb + (((kt + 1) & (Nz / 2 / 256 - 1)) * 256);

        float acc[8][8];
#pragma unroll
        for (int q = 0; q < 8; ++q)
#pragma unroll
            for (int k = 0; k < 8; ++k) acc[q][k] = 0.f;

#pragma unroll 1
        for (int cp = 0; cp < 8; ++cp) {
            const int e = 2 * cp;
            WRITECHUNK(st0, bufA);
            __syncthreads();
            LOADCHUNK(st1, kj0, e + 1);
            COMPUTECHUNK(bufA, e);
            WRITECHUNK(st1, bufB);
            __syncthreads();
            if (e == 14) { LOADCHUNK(st0, kjn, 0); }
            else         { LOADCHUNK(st0, kj0, e + 2); }
            COMPUTECHUNK(bufB, e + 1);
        }
        __syncthreads();   // bufB reads done before sc (aliased) is written

        // ---- selection: four 64-col phases over the aliased sc tile ----
        float4 xxlo = *(const float4*)&xxg[b * Nz + kj0 + tx * 4];
        float4 xxhi = *(const float4*)&xxg[b * Nz + kj0 + 128 + tx * 4];
        float xxa[8] = {xxlo.x, xxlo.y, xxlo.z, xxlo.w,
                        xxhi.x, xxhi.y, xxhi.z, xxhi.w};
        const int txh = tx >> 4;          // which 64-col half this thread owns
        const int cl0 = (tx & 15) * 4;    // col base within a phase

#pragma unroll
        for (int h = 0; h < 4; ++h) {
            // phase h = global cols [kj0+h*64, kj0+h*64+64)
            if (txh == (h & 1)) {
                const int qs = (h >> 1) * 4;   // acc quad: 0..3 or 4..7
#pragma unroll
                for (int dq = 0; dq < 8; ++dq) {
                    int r = ty * 8 + dq;
                    float4 w;
                    w.x = 2.f * acc[dq][qs + 0] - xxa[qs + 0];
                    w.y = 2.f * acc[dq][qs + 1] - xxa[qs + 1];
                    w.z = 2.f * acc[dq][qs + 2] - xxa[qs + 2];
                    w.w = 2.f * acc[dq][qs + 3] - xxa[qs + 3];
                    *(float4*)&sc[r * 64 + ((cl0 + 4 * r) & 63)] = w;
                }
            }
            __syncthreads();

            // scan: lane (srow, part) covers 16 cols
            float wvb = __shfl(wv, lane & 15);
            unsigned m = 0;
#pragma unroll
            for (int g = 0; g < 4; ++g) {
                int col = part * 16 + g * 4;
                float4 v = *(const float4*)&sc[srow * 64 + ((col + 4 * srow) & 63)];
                m |= (unsigned)(v.x > wvb) << (4 * g + 0);
                m |= (unsigned)(v.y > wvb) << (4 * g + 1);
                m |= (unsigned)(v.z > wvb) << (4 * g + 2);
                m |= (unsigned)(v.w > wvb) << (4 * g + 3);
            }
            unsigned long long f = (unsigned long long)m << (16 * part);
            f |= __shfl_xor(f, 16);
            f |= __shfl_xor(f, 32);
            if (lane < 16) { EXTRACT(f, kj0 + h * 64); }
            __syncthreads();   // extraction done before next write (phase/tile)
        }
    }

    if (lane < 16) {
        size_t base = ((size_t)hz * Bz * Nz + (size_t)b * Nz + q0 + orow) * Kz;
#pragma unroll
        for (int s = 0; s < Kz; ++s) { pval[base + s] = tv[s]; pidx[base + s] = ti[s]; }
    }
#undef LOADCHUNK
#undef WRITECHUNK
#undef COMPUTECHUNK
#undef EXTRACT
}

// ---------------------------------------------------------------------------
// Kernel 2b: merge the two per-half top-20 lists exactly.
// One thread per row. State starts as half-0's 20 entries; half-1 candidates
// inserted under lexicographic (value desc, index asc) order. In the tie-free
// case (generic fp32 data) this equals the single full ascending-j scan.
// ---------------------------------------------------------------------------
__global__ __launch_bounds__(256) void merge_kernel(const float* __restrict__ pval,
                                                    const int* __restrict__ pidx,
                                                    int* __restrict__ idxout) {
    const int r = blockIdx.x * 256 + threadIdx.x;    // 0 .. B*N-1
    const float* v0 = pval + (size_t)r * Kz;
    const float* v1 = pval + ((size_t)Bz * Nz + r) * Kz;
    const int*   i0 = pidx + (size_t)r * Kz;
    const int*   i1 = pidx + ((size_t)Bz * Nz + r) * Kz;

    float tv[Kz]; int ti[Kz];
#pragma unroll
    for (int s = 0; s < Kz; ++s) { tv[s] = v0[s]; ti[s] = i0[s]; }
    float wv = tv[0]; int wi = ti[0]; int wslot = 0;
#pragma unroll
    for (int s = 1; s < Kz; ++s) {
        bool worse = (tv[s] < wv) || (tv[s] == wv && ti[s] > wi);
        if (worse) { wv = tv[s]; wi = ti[s]; wslot = s; }
    }
#pragma unroll 1
    for (int c = 0; c < Kz; ++c) {
        float cv = v1[c]; int ci = i1[c];
        bool better = (cv > wv) || (cv == wv && ci < wi);
        if (better) {
#pragma unroll
            for (int s = 0; s < Kz; ++s) {
                bool hit = (s == wslot);
                tv[s] = hit ? cv : tv[s];
                ti[s] = hit ? ci : ti[s];
            }
            wv = tv[0]; wi = ti[0]; wslot = 0;
#pragma unroll
            for (int s = 1; s < Kz; ++s) {
                bool worse = (tv[s] < wv) || (tv[s] == wv && ti[s] > wi);
                if (worse) { wv = tv[s]; wi = ti[s]; wslot = s; }
            }
        }
    }
    size_t base = (size_t)r * Kz;
#pragma unroll
    for (int s = 0; s < Kz; ++s) idxout[base + s] = ti[s];
}

// ---------------------------------------------------------------------------
// Kernel 3: Y[p][o'] (unchanged)
// ---------------------------------------------------------------------------
__global__ __launch_bounds__(256) void feat_kernel(const float* __restrict__ x,
                                                   const float* __restrict__ W,
                                                   const float* __restrict__ bias,
                                                   float* __restrict__ Y) {
    const int gp0 = blockIdx.x * 64;         // global point index (b*N+n)
    const int b   = gp0 >> 13;
    const int n0  = gp0 & (Nz - 1);
    const int o0  = blockIdx.y * 64;

    __shared__ __align__(16) float xt[128 * 64];   // [c][p]
    __shared__ __align__(16) float wt[128 * 64];   // [c][o']

    const int tid = threadIdx.x;
    const int tx  = tid & 15;
    const int ty  = tid >> 4;

    {
        int li = tid & 63;
        int c0 = tid >> 6;
        const float* xbp = x + (size_t)b * Cz * Nz + n0;
#pragma unroll
        for (int rep = 0; rep < 32; ++rep) {
            int c = c0 + rep * 4;
            xt[c * 64 + li] = xbp[(size_t)c * Nz + li];
        }
    }
    {
        int lo = tid & 63;
        int c0 = tid >> 6;
        int oo = o0 + lo;
#pragma unroll
        for (int rep = 0; rep < 32; ++rep) {
            int c = c0 + rep * 4;
            float w;
            if (oo < 128) w = W[oo * 256 + c] + W[oo * 256 + 128 + c];
            else          w = W[(oo - 128) * 256 + 128 + c];
            wt[c * 64 + lo] = w;
        }
    }
    __syncthreads();

    float acc[4][4];
#pragma unroll
    for (int di = 0; di < 4; ++di)
#pragma unroll
        for (int dj = 0; dj < 4; ++dj) acc[di][dj] = 0.f;

    const int aoff = ty * 4;
    const int boff = tx * 4;
#pragma unroll 8
    for (int c = 0; c < 128; ++c) {
        float4 a  = *(const float4*)&xt[c * 64 + aoff];
        float4 ww = *(const float4*)&wt[c * 64 + boff];
        float av[4] = {a.x, a.y, a.z, a.w};
        float wvv[4] = {ww.x, ww.y, ww.z, ww.w};
#pragma unroll
        for (int di = 0; di < 4; ++di)
#pragma unroll
            for (int dj = 0; dj < 4; ++dj)
                acc[di][dj] = fmaf(av[di], wvv[dj], acc[di][dj]);
    }

    float4 bv = make_float4(0.f, 0.f, 0.f, 0.f);
    if (o0 < 128) bv = *(const float4*)&bias[o0 + tx * 4];
#pragma unroll
    for (int di = 0; di < 4; ++di) {
        float4 r;
        r.x = acc[di][0] + bv.x;
        r.y = acc[di][1] + bv.y;
        r.z = acc[di][2] + bv.z;
        r.w = acc[di][3] + bv.w;
        *(float4*)&Y[(size_t)(gp0 + ty * 4 + di) * 256 + o0 + tx * 4] = r;
    }
}

// ---------------------------------------------------------------------------
// Kernel 4: out[b][o][n] = relu(u[n][o] - min_j v[idx[n][j]][o])  (unchanged)
// ---------------------------------------------------------------------------
__global__ __launch_bounds__(256) void gather_kernel(const int* __restrict__ idxg,
                                                     const float* __restrict__ Y,
                                                     float* __restrict__ out) {
    const int gp0 = blockIdx.x * 64;
    const int b   = gp0 >> 13;
    const int n0  = gp0 & (Nz - 1);

    __shared__ int lidx[64 * 21];
    const int tid = threadIdx.x;
    for (int t = tid; t < 64 * Kz; t += 256) {
        int p = t / Kz, j = t - p * Kz;
        lidx[p * 21 + j] = idxg[(size_t)(gp0 + p) * Kz + j];
    }
    __syncthreads();

    const int p  = tid & 63;
    const int o0 = (tid >> 6) * 32;

    float mn[32];
#pragma unroll
    for (int q = 0; q < 32; ++q) mn[q] = FLT_MAX;

    for (int j = 0; j < Kz; ++j) {
        int m = lidx[p * 21 + j];
        const float4* vr =
            (const float4*)(Y + (size_t)(b * Nz + m) * 256 + 128 + o0);
#pragma unroll
        for (int q = 0; q < 8; ++q) {
            float4 v4 = vr[q];
            mn[4 * q + 0] = fminf(mn[4 * q + 0], v4.x);
            mn[4 * q + 1] = fminf(mn[4 * q + 1], v4.y);
            mn[4 * q + 2] = fminf(mn[4 * q + 2], v4.z);
            mn[4 * q + 3] = fminf(mn[4 * q + 3], v4.w);
        }
    }

    const float4* ur = (const float4*)(Y + (size_t)(gp0 + p) * 256 + o0);
#pragma unroll
    for (int q = 0; q < 8; ++q) {
        float4 u4 = ur[q];
        float r0 = fmaxf(u4.x - mn[4 * q + 0], 0.f);
        float r1 = fmaxf(u4.y - mn[4 * q + 1], 0.f);
        float r2 = fmaxf(u4.z - mn[4 * q + 2], 0.f);
        float r3 = fmaxf(u4.w - mn[4 * q + 3], 0.f);
        size_t ob = ((size_t)b * OUTz + o0 + 4 * q) * Nz + n0 + p;
        out[ob + 0 * Nz] = r0;
        out[ob + 1 * Nz] = r1;
        out[ob + 2 * Nz] = r2;
        out[ob + 3 * Nz] = r3;
    }
}

// ---------------------------------------------------------------------------
extern "C" void kernel_launch(void* const* d_in, const int* in_sizes, int n_in,
                              void* d_out, int out_size, void* d_ws, size_t ws_size,
                              hipStream_t stream) {
    const float* x    = (const float*)d_in[0];
    const float* W    = (const float*)d_in[1];
    const float* bias = (const float*)d_in[2];
    float* out = (float*)d_out;

    char* ws = (char*)d_ws;
    float* xx   = (float*)ws;                      // 128KB  @ 0
    int*   idx  = (int*)(ws + (1 << 17));          // 2.62MB @ 128KB
    float* pval = (float*)(ws + (4 << 20));        // 5.24MB @ 4MB   (dead after merge)
    int*   pidx = (int*)(ws + (10 << 20));         // 5.24MB @ 10MB  (dead after merge)
    float* Y    = (float*)(ws + (4 << 20));        // 32MB   @ 4MB   (written after merge)

    xx_kernel<<<dim3(Bz * Nz / 256), dim3(256), 0, stream>>>(x, xx);

    knn_kernel<<<dim3(Nz / 64, Bz, 2), dim3(256), 0, stream>>>(x, xx, pval, pidx);

    merge_kernel<<<dim3(Bz * Nz / 256), dim3(256), 0, stream>>>(pval, pidx, idx);

    feat_kernel<<<dim3(Bz * Nz / 64, 4), dim3(256), 0, stream>>>(x, W, bias, Y);

    gather_kernel<<<dim3(Bz * Nz / 64), dim3(256), 0, stream>>>(idx, Y, out);
}